// Round 1
// baseline (1388.167 us; speedup 1.0000x reference)
//
#include <hip/hip_runtime.h>

typedef _Float16 h16;
typedef _Float16 h16x4 __attribute__((ext_vector_type(4)));
typedef _Float16 h16x8 __attribute__((ext_vector_type(8)));
typedef float f32x4 __attribute__((ext_vector_type(4)));

static constexpr int NN   = 20000;   // nodes
static constexpr int NPAD = 20032;   // padded to 64-row tiles
static constexpr int NE0  = 120000;  // raw edges
static constexpr int NE   = 140000;  // + self loops
static constexpr int NG   = 512;     // graphs
static constexpr int FIN  = 300;
static constexpr int K1P  = 320;     // FIN padded to K%32==0
static constexpr int CD   = 256;     // channels per head
static constexpr float SLOPE = 0.2f;

// ---------- input conversion ----------
__global__ __launch_bounds__(256) void fill_x_kernel(const float* __restrict__ x, h16* __restrict__ a1) {
  int r = blockIdx.x;
  for (int c = threadIdx.x; c < K1P; c += 256) {
    float v = (r < NN && c < FIN) ? x[(size_t)r * FIN + c] : 0.f;
    a1[(size_t)r * K1P + c] = (h16)v;
  }
}

__global__ __launch_bounds__(256) void conv_w_kernel(const float* __restrict__ w, h16* __restrict__ o,
                                                     int cols, int colsp) {
  int r = blockIdx.x;
  for (int c = threadIdx.x; c < colsp; c += 256) {
    float v = (c < cols) ? w[(size_t)r * cols + c] : 0.f;
    o[(size_t)r * colsp + c] = (h16)v;
  }
}

// ---------- CSR build ----------
__global__ __launch_bounds__(256) void build_edges_kernel(const int* __restrict__ ei,
                                                          int* __restrict__ src, int* __restrict__ dst) {
  int e = blockIdx.x * 256 + threadIdx.x;
  if (e >= NE) return;
  if (e < NE0) { src[e] = ei[e]; dst[e] = ei[NE0 + e]; }
  else         { src[e] = e - NE0; dst[e] = e - NE0; }
}

__global__ __launch_bounds__(256) void deg_kernel(const int* __restrict__ dst, int* __restrict__ deg) {
  int e = blockIdx.x * 256 + threadIdx.x;
  if (e < NE) atomicAdd(&deg[dst[e]], 1);
}

__global__ __launch_bounds__(1024) void scan_kernel(const int* __restrict__ deg, int* __restrict__ rowptr) {
  __shared__ int b0[1024], b1[1024];
  __shared__ int carry;
  int t = threadIdx.x;
  if (t == 0) carry = 0;
  __syncthreads();
  for (int base = 0; base < NN; base += 1024) {
    int x = (base + t < NN) ? deg[base + t] : 0;
    b0[t] = x;
    __syncthreads();
    int* cur = b0; int* nxt = b1;
    for (int off = 1; off < 1024; off <<= 1) {
      int v = cur[t];
      if (t >= off) v += cur[t - off];
      nxt[t] = v;
      __syncthreads();
      int* tmp = cur; cur = nxt; nxt = tmp;
    }
    if (base + t < NN) rowptr[base + t] = carry + cur[t] - x;  // exclusive
    __syncthreads();
    if (t == 0) carry += cur[1023];
    __syncthreads();
  }
  if (t == 0) rowptr[NN] = carry;
}

__global__ __launch_bounds__(256) void scatter_kernel(const int* __restrict__ dst, const int* __restrict__ rowptr,
                                                      int* __restrict__ cursor, int* __restrict__ eidx) {
  int e = blockIdx.x * 256 + threadIdx.x;
  if (e >= NE) return;
  int d = dst[e];
  int pos = rowptr[d] + atomicAdd(&cursor[d], 1);
  eidx[pos] = e;
}

// ---------- fp16 MFMA GEMM: C[M,Nw] = A[M,K] * B[Nw,K]^T  (B is K-major weight) ----------
__global__ __launch_bounds__(256) void gemm_kernel(const h16* __restrict__ A, const h16* __restrict__ B,
                                                   h16* __restrict__ Co, int K, int Nw) {
  constexpr int LDT = 40;  // padded LDS row stride (bank-conflict break)
  __shared__ __align__(16) h16 As[64 * LDT];
  __shared__ __align__(16) h16 Bs[64 * LDT];
  int tid = threadIdx.x;
  int tm = blockIdx.x * 64, tn = blockIdx.y * 64;
  int wave = tid >> 6, lane = tid & 63;
  int wm = (wave >> 1) * 32, wn = (wave & 1) * 32;
  int srow = tid >> 2, scol = (tid & 3) * 8;
  const h16* Ap = A + (size_t)(tm + srow) * K + scol;
  const h16* Bp = B + (size_t)(tn + srow) * K + scol;
  int lrow = lane & 15, kg = (lane >> 4) * 8;
  f32x4 acc00 = {}, acc01 = {}, acc10 = {}, acc11 = {};
  for (int k0 = 0; k0 < K; k0 += 32) {
    uint4 av = *(const uint4*)(Ap + k0);
    uint4 bv = *(const uint4*)(Bp + k0);
    __syncthreads();
    *(uint4*)&As[srow * LDT + scol] = av;
    *(uint4*)&Bs[srow * LDT + scol] = bv;
    __syncthreads();
    h16x8 a0 = *(const h16x8*)&As[(wm + lrow) * LDT + kg];
    h16x8 a1 = *(const h16x8*)&As[(wm + 16 + lrow) * LDT + kg];
    h16x8 b0 = *(const h16x8*)&Bs[(wn + lrow) * LDT + kg];
    h16x8 b1 = *(const h16x8*)&Bs[(wn + 16 + lrow) * LDT + kg];
    acc00 = __builtin_amdgcn_mfma_f32_16x16x32_f16(a0, b0, acc00, 0, 0, 0);
    acc01 = __builtin_amdgcn_mfma_f32_16x16x32_f16(a0, b1, acc01, 0, 0, 0);
    acc10 = __builtin_amdgcn_mfma_f32_16x16x32_f16(a1, b0, acc10, 0, 0, 0);
    acc11 = __builtin_amdgcn_mfma_f32_16x16x32_f16(a1, b1, acc11, 0, 0, 0);
  }
  int cr = (lane >> 4) * 4, cc = lane & 15;
  f32x4 accs[2][2] = {{acc00, acc01}, {acc10, acc11}};
  for (int i = 0; i < 2; i++)
    for (int j = 0; j < 2; j++)
      for (int r = 0; r < 4; r++) {
        int row = tm + wm + i * 16 + cr + r;
        if (row < NN) Co[(size_t)row * Nw + (tn + wn + j * 16 + cc)] = (h16)accs[i][j][r];
      }
}

// ---------- per-edge attention scores ----------
template <int H>
__global__ __launch_bounds__(256) void score_kernel(const h16* __restrict__ XL, const h16* __restrict__ XR,
                                                    const float* __restrict__ att, const int* __restrict__ src,
                                                    const int* __restrict__ dst, float* __restrict__ scores) {
  int e = blockIdx.x * 4 + (threadIdx.x >> 6);
  if (e >= NE) return;
  int lane = threadIdx.x & 63;
  const h16* xl = XL + (size_t)src[e] * (H * CD);
  const h16* xr = XR + (size_t)dst[e] * (H * CD);
#pragma unroll
  for (int h = 0; h < H; ++h) {
    int cb = h * CD + lane * 4;
    h16x4 a = *(const h16x4*)(xl + cb);
    h16x4 b = *(const h16x4*)(xr + cb);
    float4 w4 = *(const float4*)(att + cb);
    const float* wv = (const float*)&w4;
    float acc = 0.f;
#pragma unroll
    for (int j = 0; j < 4; ++j) {
      float v = (float)a[j] + (float)b[j];
      v = v > 0.f ? v : SLOPE * v;
      acc += v * wv[j];
    }
    for (int off = 32; off > 0; off >>= 1) acc += __shfl_xor(acc, off);
    if (lane == 0) scores[(size_t)e * H + h] = acc;
  }
}

// ---------- per-node softmax + aggregation (CSR) ----------
// MODE 0: out = elu(agg + bias) -> fp16 buf (ld = H*CD).  MODE 1: out = mean_h(agg) + bias -> fp32 (ld = CD)
template <int H, int MODE>
__global__ __launch_bounds__(256) void agg_kernel(const h16* __restrict__ XL, const float* __restrict__ scores,
                                                  const int* __restrict__ rowptr, const int* __restrict__ eidx,
                                                  const int* __restrict__ src, const float* __restrict__ bias,
                                                  h16* __restrict__ outA, float* __restrict__ outF) {
  constexpr int CHK = 32;
  __shared__ float s_mx[H], s_inv[H];
  __shared__ float s_al[CHK][H];
  __shared__ int s_src[CHK];
  int n = blockIdx.x, tid = threadIdx.x;
  int beg = rowptr[n], end = rowptr[n + 1];
  if (tid < H) {
    float m = -1e30f;
    for (int i = beg; i < end; ++i) m = fmaxf(m, scores[(size_t)eidx[i] * H + tid]);
    float s = 0.f;
    for (int i = beg; i < end; ++i) s += __expf(scores[(size_t)eidx[i] * H + tid] - m);
    s_mx[tid] = m;
    s_inv[tid] = 1.f / (s + 1e-16f);
  }
  __syncthreads();
  float acc[H] = {0.f};
  for (int cb = beg; cb < end; cb += CHK) {
    int cn = min(CHK, end - cb);
    if (tid < cn * H) {
      int i = tid / H, j = tid - i * H;
      int e = eidx[cb + i];
      s_al[i][j] = __expf(scores[(size_t)e * H + j] - s_mx[j]) * s_inv[j];
      if (j == 0) s_src[i] = src[e];
    }
    __syncthreads();
    for (int i = 0; i < cn; ++i) {
      const h16* row = XL + (size_t)s_src[i] * (H * CD) + tid;
#pragma unroll
      for (int j = 0; j < H; ++j) acc[j] += s_al[i][j] * (float)row[j * CD];
    }
    __syncthreads();
  }
  if (MODE == 0) {
#pragma unroll
    for (int j = 0; j < H; ++j) {
      float v = acc[j] + bias[j * CD + tid];
      v = v > 0.f ? v : expm1f(v);
      outA[(size_t)n * (H * CD) + j * CD + tid] = (h16)v;
    }
  } else {
    float v = 0.f;
#pragma unroll
    for (int j = 0; j < H; ++j) v += acc[j];
    v = v * (1.f / H) + bias[tid];
    outF[(size_t)n * CD + tid] = v;
  }
}

// ---------- L2 normalize + mean pool ----------
__global__ __launch_bounds__(256) void norm_pool_kernel(const float* __restrict__ F, const int* __restrict__ batch,
                                                        float* __restrict__ pooled, int* __restrict__ cnt) {
  int n = blockIdx.x, t = threadIdx.x;
  float v = F[(size_t)n * CD + t];
  float ss = v * v;
  for (int off = 32; off > 0; off >>= 1) ss += __shfl_xor(ss, off);
  __shared__ float ws4[4];
  if ((t & 63) == 0) ws4[t >> 6] = ss;
  __syncthreads();
  float tot = ws4[0] + ws4[1] + ws4[2] + ws4[3];
  float scale = 1.f / fmaxf(sqrtf(tot), 1e-12f);
  int g = batch[n];
  atomicAdd(&pooled[(size_t)g * CD + t], v * scale);
  if (t == 0) atomicAdd(&cnt[g], 1);
}

__global__ __launch_bounds__(256) void pool_div_kernel(float* __restrict__ pooled, const int* __restrict__ cnt) {
  int g = blockIdx.x, t = threadIdx.x;
  pooled[(size_t)g * CD + t] /= fmaxf((float)cnt[g], 1.f);
}

// ---------- tiny fp32 MLP ----------
__global__ __launch_bounds__(256) void mlp1_kernel(const float* __restrict__ pooled, const float* __restrict__ w,
                                                   const float* __restrict__ b, float* __restrict__ hid) {
  __shared__ float xs[CD];
  int g = blockIdx.x, t = threadIdx.x;
  xs[t] = pooled[(size_t)g * CD + t];
  __syncthreads();
  float acc = b[t];
  for (int k = 0; k < CD; ++k) acc += xs[k] * w[(size_t)t * CD + k];
  hid[(size_t)g * CD + t] = fmaxf(acc, 0.f);
}

__global__ __launch_bounds__(256) void mlp2_kernel(const float* __restrict__ hid, const float* __restrict__ w,
                                                   const float* __restrict__ b, float* __restrict__ out) {
  __shared__ float xs[CD];
  int g = blockIdx.x, t = threadIdx.x;
  xs[t] = hid[(size_t)g * CD + t];
  __syncthreads();
  for (int o = t; o < 768; o += 256) {
    float acc = b[o];
    for (int k = 0; k < CD; ++k) acc += xs[k] * w[(size_t)o * CD + k];
    out[(size_t)g * 768 + o] = acc;
  }
}

extern "C" void kernel_launch(void* const* d_in, const int* in_sizes, int n_in,
                              void* d_out, int out_size, void* d_ws, size_t ws_size,
                              hipStream_t stream) {
  const float* x      = (const float*)d_in[0];
  const int*   ei     = (const int*)d_in[1];
  const int*   batch  = (const int*)d_in[2];
  const float* c1_wl  = (const float*)d_in[3];
  const float* c1_wr  = (const float*)d_in[4];
  const float* c1_att = (const float*)d_in[5];
  const float* c1_b   = (const float*)d_in[6];
  const float* c2_wl  = (const float*)d_in[7];
  const float* c2_wr  = (const float*)d_in[8];
  const float* c2_att = (const float*)d_in[9];
  const float* c2_b   = (const float*)d_in[10];
  const float* c3_wl  = (const float*)d_in[11];
  const float* c3_wr  = (const float*)d_in[12];
  const float* c3_att = (const float*)d_in[13];
  const float* c3_b   = (const float*)d_in[14];
  const float* fp1_w  = (const float*)d_in[15];
  const float* fp1_b  = (const float*)d_in[16];
  const float* fp2_w  = (const float*)d_in[17];
  const float* fp2_b  = (const float*)d_in[18];

  char* p = (char*)d_ws;
  size_t off = 0;
  auto alloc = [&](size_t b) { void* r = p + off; off += (b + 255) & ~(size_t)255; return r; };
  h16*  A1     = (h16*)alloc((size_t)NPAD * K1P * 2);
  h16*  A      = (h16*)alloc((size_t)NPAD * 1024 * 2);
  h16*  XL     = (h16*)alloc((size_t)NN * 1536 * 2);
  h16*  XR     = (h16*)alloc((size_t)NN * 1536 * 2);
  float* Fb    = (float*)alloc((size_t)NN * CD * 4);
  h16*  W1L    = (h16*)alloc((size_t)1024 * K1P * 2);
  h16*  W1R    = (h16*)alloc((size_t)1024 * K1P * 2);
  h16*  W2L    = (h16*)alloc((size_t)1024 * 1024 * 2);
  h16*  W2R    = (h16*)alloc((size_t)1024 * 1024 * 2);
  h16*  W3L    = (h16*)alloc((size_t)1536 * 1024 * 2);
  h16*  W3R    = (h16*)alloc((size_t)1536 * 1024 * 2);
  float* scores = (float*)alloc((size_t)NE * 6 * 4);
  int*  srcA   = (int*)alloc((size_t)NE * 4);
  int*  dstA   = (int*)alloc((size_t)NE * 4);
  int*  eidx   = (int*)alloc((size_t)NE * 4);
  int*  deg    = (int*)alloc((size_t)NN * 4);
  int*  cursor = (int*)alloc((size_t)NN * 4);
  int*  rowptr = (int*)alloc((size_t)(NN + 1) * 4);
  float* pooled = (float*)alloc((size_t)NG * CD * 4);
  int*  cnt    = (int*)alloc((size_t)NG * 4);
  float* hid   = (float*)alloc((size_t)NG * CD * 4);

  hipMemsetAsync(deg, 0, (size_t)NN * 4, stream);
  hipMemsetAsync(cursor, 0, (size_t)NN * 4, stream);
  hipMemsetAsync(pooled, 0, (size_t)NG * CD * 4, stream);
  hipMemsetAsync(cnt, 0, (size_t)NG * 4, stream);
  hipMemsetAsync(A + (size_t)NN * 1024, 0, (size_t)(NPAD - NN) * 1024 * 2, stream);  // pad rows

  fill_x_kernel<<<NPAD, 256, 0, stream>>>(x, A1);
  conv_w_kernel<<<1024, 256, 0, stream>>>(c1_wl, W1L, FIN, K1P);
  conv_w_kernel<<<1024, 256, 0, stream>>>(c1_wr, W1R, FIN, K1P);
  conv_w_kernel<<<1024, 256, 0, stream>>>(c2_wl, W2L, 1024, 1024);
  conv_w_kernel<<<1024, 256, 0, stream>>>(c2_wr, W2R, 1024, 1024);
  conv_w_kernel<<<1536, 256, 0, stream>>>(c3_wl, W3L, 1024, 1024);
  conv_w_kernel<<<1536, 256, 0, stream>>>(c3_wr, W3R, 1024, 1024);

  int eb = (NE + 255) / 256;
  build_edges_kernel<<<eb, 256, 0, stream>>>(ei, srcA, dstA);
  deg_kernel<<<eb, 256, 0, stream>>>(dstA, deg);
  scan_kernel<<<1, 1024, 0, stream>>>(deg, rowptr);
  scatter_kernel<<<eb, 256, 0, stream>>>(dstA, rowptr, cursor, eidx);

  dim3 g1(313, 16);
  gemm_kernel<<<g1, 256, 0, stream>>>(A1, W1L, XL, K1P, 1024);
  gemm_kernel<<<g1, 256, 0, stream>>>(A1, W1R, XR, K1P, 1024);
  score_kernel<4><<<(NE + 3) / 4, 256, 0, stream>>>(XL, XR, c1_att, srcA, dstA, scores);
  agg_kernel<4, 0><<<NN, 256, 0, stream>>>(XL, scores, rowptr, eidx, srcA, c1_b, A, nullptr);

  gemm_kernel<<<g1, 256, 0, stream>>>(A, W2L, XL, 1024, 1024);
  gemm_kernel<<<g1, 256, 0, stream>>>(A, W2R, XR, 1024, 1024);
  score_kernel<4><<<(NE + 3) / 4, 256, 0, stream>>>(XL, XR, c2_att, srcA, dstA, scores);
  agg_kernel<4, 0><<<NN, 256, 0, stream>>>(XL, scores, rowptr, eidx, srcA, c2_b, A, nullptr);

  dim3 g3(313, 24);
  gemm_kernel<<<g3, 256, 0, stream>>>(A, W3L, XL, 1024, 1536);
  gemm_kernel<<<g3, 256, 0, stream>>>(A, W3R, XR, 1024, 1536);
  score_kernel<6><<<(NE + 3) / 4, 256, 0, stream>>>(XL, XR, c3_att, srcA, dstA, scores);
  agg_kernel<6, 1><<<NN, 256, 0, stream>>>(XL, scores, rowptr, eidx, srcA, c3_b, nullptr, Fb);

  norm_pool_kernel<<<NN, 256, 0, stream>>>(Fb, batch, pooled, cnt);
  pool_div_kernel<<<NG, 256, 0, stream>>>(pooled, cnt);
  mlp1_kernel<<<NG, 256, 0, stream>>>(pooled, fp1_w, fp1_b, hid);
  mlp2_kernel<<<NG, 256, 0, stream>>>(hid, fp2_w, fp2_b, (float*)d_out);
}

// Round 2
// 777.440 us; speedup vs baseline: 1.7856x; 1.7856x over previous
//
#include <hip/hip_runtime.h>

typedef _Float16 h16;
typedef _Float16 h16x4 __attribute__((ext_vector_type(4)));
typedef _Float16 h16x8 __attribute__((ext_vector_type(8)));
typedef float f32x4 __attribute__((ext_vector_type(4)));

static constexpr int NN   = 20000;   // nodes
static constexpr int NPAD = 20096;   // padded to 128-row tiles (157*128)
static constexpr int NE0  = 120000;  // raw edges
static constexpr int NE   = 140000;  // + self loops
static constexpr int NG   = 512;     // graphs
static constexpr int FIN  = 300;
static constexpr int K1P  = 320;     // FIN padded to K%32==0
static constexpr int CD   = 256;     // channels per head
static constexpr float SLOPE = 0.2f;

#define GLDS16(gsrc, ldst)                                                              \
  __builtin_amdgcn_global_load_lds(                                                    \
      (const __attribute__((address_space(1))) unsigned int*)(gsrc),                    \
      (__attribute__((address_space(3))) unsigned int*)(ldst), 16, 0, 0)

// ---------- input conversion ----------
__global__ __launch_bounds__(256) void fill_x_kernel(const float* __restrict__ x, h16* __restrict__ a1) {
  int r = blockIdx.x;
  for (int c = threadIdx.x; c < K1P; c += 256) {
    float v = (r < NN && c < FIN) ? x[(size_t)r * FIN + c] : 0.f;
    a1[(size_t)r * K1P + c] = (h16)v;
  }
}

// stacked [WL; WR] -> fp16, K padded
__global__ __launch_bounds__(256) void conv_w2_kernel(const float* __restrict__ wl, const float* __restrict__ wr,
                                                      h16* __restrict__ o, int rows, int cols, int colsp) {
  int r = blockIdx.x;  // 0 .. 2*rows-1
  const float* s = (r < rows) ? (wl + (size_t)r * cols) : (wr + (size_t)(r - rows) * cols);
  for (int c = threadIdx.x; c < colsp; c += 256) {
    float v = (c < cols) ? s[c] : 0.f;
    o[(size_t)r * colsp + c] = (h16)v;
  }
}

// ---------- CSR build ----------
__global__ __launch_bounds__(256) void build_edges_kernel(const int* __restrict__ ei,
                                                          int* __restrict__ src, int* __restrict__ dst) {
  int e = blockIdx.x * 256 + threadIdx.x;
  if (e >= NE) return;
  if (e < NE0) { src[e] = ei[e]; dst[e] = ei[NE0 + e]; }
  else         { src[e] = e - NE0; dst[e] = e - NE0; }
}

__global__ __launch_bounds__(256) void deg_kernel(const int* __restrict__ dst, int* __restrict__ deg) {
  int e = blockIdx.x * 256 + threadIdx.x;
  if (e < NE) atomicAdd(&deg[dst[e]], 1);
}

__global__ __launch_bounds__(1024) void scan_kernel(const int* __restrict__ deg, int* __restrict__ rowptr) {
  __shared__ int b0[1024], b1[1024];
  __shared__ int carry;
  int t = threadIdx.x;
  if (t == 0) carry = 0;
  __syncthreads();
  for (int base = 0; base < NN; base += 1024) {
    int x = (base + t < NN) ? deg[base + t] : 0;
    b0[t] = x;
    __syncthreads();
    int* cur = b0; int* nxt = b1;
    for (int off = 1; off < 1024; off <<= 1) {
      int v = cur[t];
      if (t >= off) v += cur[t - off];
      nxt[t] = v;
      __syncthreads();
      int* tmp = cur; cur = nxt; nxt = tmp;
    }
    if (base + t < NN) rowptr[base + t] = carry + cur[t] - x;  // exclusive
    __syncthreads();
    if (t == 0) carry += cur[1023];
    __syncthreads();
  }
  if (t == 0) rowptr[NN] = carry;
}

// scatter: store SOURCE NODE (not edge id) sorted by dst
__global__ __launch_bounds__(256) void scatter_kernel(const int* __restrict__ src, const int* __restrict__ dst,
                                                      const int* __restrict__ rowptr, int* __restrict__ cursor,
                                                      int* __restrict__ esrc) {
  int e = blockIdx.x * 256 + threadIdx.x;
  if (e >= NE) return;
  int d = dst[e];
  int pos = rowptr[d] + atomicAdd(&cursor[d], 1);
  esrc[pos] = src[e];
}

// ---------- fp16 MFMA GEMM (m97 structure): C[M,Nw] = A[M,K] * B[Nw,K]^T ----------
// 128x128 tile, BK=32, 4 waves (each 64x64), global_load_lds width 16, linear LDS,
// bijective XCD swizzle + y-fastest tile order for L2 A-panel locality.
__global__ __launch_bounds__(256) void gemm_kernel(const h16* __restrict__ A, const h16* __restrict__ B,
                                                   h16* __restrict__ Co, int K, int Nw, int ntN) {
  __shared__ __align__(16) h16 As[128 * 32];
  __shared__ __align__(16) h16 Bs[128 * 32];
  int nwg = gridDim.x;
  int q = nwg >> 3, r = nwg & 7;
  int xc = blockIdx.x & 7, idx = blockIdx.x >> 3;
  int logical = (xc < r ? xc * (q + 1) : r * (q + 1) + (xc - r) * q) + idx;
  int tm = (logical / ntN) * 128, tn = (logical % ntN) * 128;

  int tid = threadIdx.x, w = tid >> 6, lane = tid & 63;
  int wm = (w >> 1) * 64, wn = (w & 1) * 64;
  const h16* gA = A + (size_t)(tm + w * 16 + (lane >> 2)) * K + (lane & 3) * 8;
  const h16* gB = B + (size_t)(tn + w * 16 + (lane >> 2)) * K + (lane & 3) * 8;
  h16* lA0 = As + w * 512;         // rows w*16 .. w*16+15   (1024 B per wave-issue)
  h16* lA1 = As + 2048 + w * 512;  // rows 64+w*16 ..
  h16* lB0 = Bs + w * 512;
  h16* lB1 = Bs + 2048 + w * 512;
  const size_t rowskip = (size_t)64 * K;
  int lrow = lane & 15, kg = (lane >> 4) * 8;

  f32x4 acc[4][4] = {};
  for (int k0 = 0; k0 < K; k0 += 32) {
    __syncthreads();  // previous fragments consumed before overwrite
    GLDS16(gA + k0, lA0);
    GLDS16(gA + rowskip + k0, lA1);
    GLDS16(gB + k0, lB0);
    GLDS16(gB + rowskip + k0, lB1);
    __syncthreads();  // compiler drains vmcnt before barrier -> LDS ready
    h16x8 af[4], bf[4];
#pragma unroll
    for (int i = 0; i < 4; i++) af[i] = *(const h16x8*)&As[(wm + i * 16 + lrow) * 32 + kg];
#pragma unroll
    for (int j = 0; j < 4; j++) bf[j] = *(const h16x8*)&Bs[(wn + j * 16 + lrow) * 32 + kg];
#pragma unroll
    for (int i = 0; i < 4; i++)
#pragma unroll
      for (int j = 0; j < 4; j++)
        acc[i][j] = __builtin_amdgcn_mfma_f32_16x16x32_f16(af[i], bf[j], acc[i][j], 0, 0, 0);
  }
  int cr = (lane >> 4) * 4, cc = lane & 15;
#pragma unroll
  for (int i = 0; i < 4; i++)
#pragma unroll
    for (int j = 0; j < 4; j++) {
      size_t base = (size_t)(tm + wm + i * 16 + cr) * Nw + (tn + wn + j * 16 + cc);
#pragma unroll
      for (int qq = 0; qq < 4; qq++) Co[base + (size_t)qq * Nw] = (h16)acc[i][j][qq];
    }
}

// ---------- fused score + online-softmax + aggregate ----------
// X row layout: [ xl (H*CD) | xr (H*CD) ], stride S = 2*H*CD.
// One wave per head; lane owns 4 channels. Each edge's xl row is gathered ONCE.
// MODE 0: out = elu(agg + bias) -> fp16 [NPAD][H*CD]
// MODE 1: mean over heads + bias -> L2-normalize -> atomic mean-pool accumulate
template <int H, int MODE>
__global__ __launch_bounds__(64 * H) void sagg_kernel(
    const h16* __restrict__ X, const int* __restrict__ rowptr, const int* __restrict__ esrc,
    const float* __restrict__ att, const float* __restrict__ bias,
    h16* __restrict__ outA, const int* __restrict__ batch,
    float* __restrict__ pooled, int* __restrict__ cnt) {
  constexpr int HC = H * CD, S = 2 * HC;
  int n = blockIdx.x;
  int tid = threadIdx.x, w = tid >> 6, lane = tid & 63;
  int cb = w * CD + lane * 4;

  float4 aw4 = *(const float4*)(att + cb);
  const float* aw = (const float*)&aw4;
  h16x4 xr4 = *(const h16x4*)(X + (size_t)n * S + HC + cb);
  float xr0 = (float)xr4[0], xr1 = (float)xr4[1], xr2 = (float)xr4[2], xr3 = (float)xr4[3];

  int beg = rowptr[n], end = rowptr[n + 1];
  float m = -1e30f, s = 0.f;
  float a0 = 0.f, a1 = 0.f, a2 = 0.f, a3 = 0.f;
  for (int i = beg; i < end; ++i) {
    int j = esrc[i];
    h16x4 xl4 = *(const h16x4*)(X + (size_t)j * S + cb);
    float x0 = (float)xl4[0], x1 = (float)xl4[1], x2 = (float)xl4[2], x3 = (float)xl4[3];
    float v0 = x0 + xr0, v1 = x1 + xr1, v2 = x2 + xr2, v3 = x3 + xr3;
    v0 = v0 > 0.f ? v0 : SLOPE * v0;
    v1 = v1 > 0.f ? v1 : SLOPE * v1;
    v2 = v2 > 0.f ? v2 : SLOPE * v2;
    v3 = v3 > 0.f ? v3 : SLOPE * v3;
    float p = v0 * aw[0] + v1 * aw[1] + v2 * aw[2] + v3 * aw[3];
    p += __shfl_xor(p, 32); p += __shfl_xor(p, 16); p += __shfl_xor(p, 8);
    p += __shfl_xor(p, 4);  p += __shfl_xor(p, 2);  p += __shfl_xor(p, 1);
    float nm = fmaxf(m, p);
    float f = __expf(m - nm), we = __expf(p - nm);
    s = s * f + we;
    a0 = a0 * f + we * x0; a1 = a1 * f + we * x1;
    a2 = a2 * f + we * x2; a3 = a3 * f + we * x3;
    m = nm;
  }
  float inv = 1.f / (s + 1e-16f);

  if (MODE == 0) {
    float o0 = a0 * inv + bias[cb + 0];
    float o1 = a1 * inv + bias[cb + 1];
    float o2 = a2 * inv + bias[cb + 2];
    float o3 = a3 * inv + bias[cb + 3];
    o0 = o0 > 0.f ? o0 : expm1f(o0);
    o1 = o1 > 0.f ? o1 : expm1f(o1);
    o2 = o2 > 0.f ? o2 : expm1f(o2);
    o3 = o3 > 0.f ? o3 : expm1f(o3);
    h16x4 ov = {(h16)o0, (h16)o1, (h16)o2, (h16)o3};
    *(h16x4*)(outA + (size_t)n * HC + cb) = ov;
  } else {
    __shared__ float sh[HC];
    __shared__ float red[H];
    float4 nv = {a0 * inv, a1 * inv, a2 * inv, a3 * inv};
    *(float4*)&sh[cb] = nv;
    __syncthreads();
    float mv = 0.f;
    if (tid < CD) {
#pragma unroll
      for (int h = 0; h < H; h++) mv += sh[h * CD + tid];
      mv = mv * (1.f / H) + bias[tid];
    }
    float ss = (tid < CD) ? mv * mv : 0.f;
    ss += __shfl_xor(ss, 32); ss += __shfl_xor(ss, 16); ss += __shfl_xor(ss, 8);
    ss += __shfl_xor(ss, 4);  ss += __shfl_xor(ss, 2);  ss += __shfl_xor(ss, 1);
    if (lane == 0) red[w] = ss;
    __syncthreads();
    float tot = 0.f;
#pragma unroll
    for (int h = 0; h < H; h++) tot += red[h];
    float scale = 1.f / fmaxf(sqrtf(tot), 1e-12f);
    int g = batch[n];
    if (tid < CD) atomicAdd(&pooled[(size_t)g * CD + tid], mv * scale);
    if (tid == 0) atomicAdd(&cnt[g], 1);
  }
}

// ---------- pooled epilogue ----------
__global__ __launch_bounds__(256) void pool_div_kernel(float* __restrict__ pooled, const int* __restrict__ cnt) {
  int g = blockIdx.x, t = threadIdx.x;
  pooled[(size_t)g * CD + t] /= fmaxf((float)cnt[g], 1.f);
}

__global__ __launch_bounds__(256) void mlp1_kernel(const float* __restrict__ pooled, const float* __restrict__ w,
                                                   const float* __restrict__ b, float* __restrict__ hid) {
  __shared__ float xs[CD];
  int g = blockIdx.x, t = threadIdx.x;
  xs[t] = pooled[(size_t)g * CD + t];
  __syncthreads();
  float acc = b[t];
  for (int k = 0; k < CD; ++k) acc += xs[k] * w[(size_t)t * CD + k];
  hid[(size_t)g * CD + t] = fmaxf(acc, 0.f);
}

__global__ __launch_bounds__(256) void mlp2_kernel(const float* __restrict__ hid, const float* __restrict__ w,
                                                   const float* __restrict__ b, float* __restrict__ out) {
  __shared__ float xs[CD];
  int g = blockIdx.x, t = threadIdx.x;
  xs[t] = hid[(size_t)g * CD + t];
  __syncthreads();
  for (int o = t; o < 768; o += 256) {
    float acc = b[o];
    for (int k = 0; k < CD; ++k) acc += xs[k] * w[(size_t)o * CD + k];
    out[(size_t)g * 768 + o] = acc;
  }
}

extern "C" void kernel_launch(void* const* d_in, const int* in_sizes, int n_in,
                              void* d_out, int out_size, void* d_ws, size_t ws_size,
                              hipStream_t stream) {
  const float* x      = (const float*)d_in[0];
  const int*   ei     = (const int*)d_in[1];
  const int*   batch  = (const int*)d_in[2];
  const float* c1_wl  = (const float*)d_in[3];
  const float* c1_wr  = (const float*)d_in[4];
  const float* c1_att = (const float*)d_in[5];
  const float* c1_b   = (const float*)d_in[6];
  const float* c2_wl  = (const float*)d_in[7];
  const float* c2_wr  = (const float*)d_in[8];
  const float* c2_att = (const float*)d_in[9];
  const float* c2_b   = (const float*)d_in[10];
  const float* c3_wl  = (const float*)d_in[11];
  const float* c3_wr  = (const float*)d_in[12];
  const float* c3_att = (const float*)d_in[13];
  const float* c3_b   = (const float*)d_in[14];
  const float* fp1_w  = (const float*)d_in[15];
  const float* fp1_b  = (const float*)d_in[16];
  const float* fp2_w  = (const float*)d_in[17];
  const float* fp2_b  = (const float*)d_in[18];

  char* p = (char*)d_ws;
  size_t off = 0;
  auto alloc = [&](size_t b) { void* r = p + off; off += (b + 255) & ~(size_t)255; return r; };
  h16*  A    = (h16*)alloc((size_t)NPAD * 1024 * 2);   // conv in/out feature buffer
  h16*  Xa   = (h16*)alloc((size_t)NPAD * 3072 * 2);   // X1 (2048 used) and X3 (3072)
  h16*  Xb   = (h16*)alloc((size_t)NPAD * 2048 * 2);   // X2; A1 aliases its head
  h16*  A1   = Xb;                                     // [NPAD][320] fp16 input (dead before X2 written)
  h16*  W1   = (h16*)alloc((size_t)2048 * K1P * 2);
  h16*  W2   = (h16*)alloc((size_t)2048 * 1024 * 2);
  h16*  W3   = (h16*)alloc((size_t)3072 * 1024 * 2);
  int*  srcA   = (int*)alloc((size_t)NE * 4);
  int*  dstA   = (int*)alloc((size_t)NE * 4);
  int*  esrc   = (int*)alloc((size_t)NE * 4);
  int*  deg    = (int*)alloc((size_t)NN * 4);
  int*  cursor = (int*)alloc((size_t)NN * 4);
  int*  rowptr = (int*)alloc((size_t)(NN + 1) * 4);
  float* pooled = (float*)alloc((size_t)NG * CD * 4);
  int*  cnt    = (int*)alloc((size_t)NG * 4);
  float* hid   = (float*)alloc((size_t)NG * CD * 4);

  hipMemsetAsync(deg, 0, (size_t)NN * 4, stream);
  hipMemsetAsync(cursor, 0, (size_t)NN * 4, stream);
  hipMemsetAsync(pooled, 0, (size_t)NG * CD * 4, stream);
  hipMemsetAsync(cnt, 0, (size_t)NG * 4, stream);

  fill_x_kernel<<<NPAD, 256, 0, stream>>>(x, A1);
  conv_w2_kernel<<<2048, 256, 0, stream>>>(c1_wl, c1_wr, W1, 1024, FIN, K1P);
  conv_w2_kernel<<<2048, 256, 0, stream>>>(c2_wl, c2_wr, W2, 1024, 1024, 1024);
  conv_w2_kernel<<<3072, 256, 0, stream>>>(c3_wl, c3_wr, W3, 1536, 1024, 1024);

  int eb = (NE + 255) / 256;
  build_edges_kernel<<<eb, 256, 0, stream>>>(ei, srcA, dstA);
  deg_kernel<<<eb, 256, 0, stream>>>(dstA, deg);
  scan_kernel<<<1, 1024, 0, stream>>>(deg, rowptr);
  scatter_kernel<<<eb, 256, 0, stream>>>(srcA, dstA, rowptr, cursor, esrc);

  // conv1: [NPAD,320] x [2048,320]^T -> Xa [NPAD,2048] = [XL|XR]
  gemm_kernel<<<157 * 16, 256, 0, stream>>>(A1, W1, Xa, K1P, 2048, 16);
  sagg_kernel<4, 0><<<NN, 256, 0, stream>>>(Xa, rowptr, esrc, c1_att, c1_b, A, nullptr, nullptr, nullptr);

  // conv2: [NPAD,1024] x [2048,1024]^T -> Xb
  gemm_kernel<<<157 * 16, 256, 0, stream>>>(A, W2, Xb, 1024, 2048, 16);
  sagg_kernel<4, 0><<<NN, 256, 0, stream>>>(Xb, rowptr, esrc, c2_att, c2_b, A, nullptr, nullptr, nullptr);

  // conv3: [NPAD,1024] x [3072,1024]^T -> Xa [NPAD,3072]
  gemm_kernel<<<157 * 24, 256, 0, stream>>>(A, W3, Xa, 1024, 3072, 24);
  sagg_kernel<6, 1><<<NN, 384, 0, stream>>>(Xa, rowptr, esrc, c3_att, c3_b, nullptr, batch, pooled, cnt);

  pool_div_kernel<<<NG, 256, 0, stream>>>(pooled, cnt);
  mlp1_kernel<<<NG, 256, 0, stream>>>(pooled, fp1_w, fp1_b, hid);
  mlp2_kernel<<<NG, 256, 0, stream>>>(hid, fp2_w, fp2_b, (float*)d_out);
}

// Round 3
// 725.959 us; speedup vs baseline: 1.9122x; 1.0709x over previous
//
#include <hip/hip_runtime.h>

typedef _Float16 h16;
typedef _Float16 h16x4 __attribute__((ext_vector_type(4)));
typedef _Float16 h16x8 __attribute__((ext_vector_type(8)));
typedef float f32x4 __attribute__((ext_vector_type(4)));

static constexpr int NN   = 20000;   // nodes
static constexpr int NPAD = 20224;   // padded to 256-row tiles (79*256)
static constexpr int NE0  = 120000;  // raw edges
static constexpr int NE   = 140000;  // + self loops
static constexpr int NG   = 512;     // graphs
static constexpr int FIN  = 300;
static constexpr int K1P  = 384;     // FIN padded to K%64==0 (3 BK-iters)
static constexpr int CD   = 256;     // channels per head
static constexpr float SLOPE = 0.2f;

#define GLDS16(gsrc, ldst)                                                              \
  __builtin_amdgcn_global_load_lds(                                                    \
      (const __attribute__((address_space(1))) unsigned int*)(gsrc),                    \
      (__attribute__((address_space(3))) unsigned int*)(ldst), 16, 0, 0)

// ---------- input conversion ----------
__global__ __launch_bounds__(256) void fill_x_kernel(const float* __restrict__ x, h16* __restrict__ a1) {
  int r = blockIdx.x;
  for (int c = threadIdx.x; c < K1P; c += 256) {
    float v = (r < NN && c < FIN) ? x[(size_t)r * FIN + c] : 0.f;
    a1[(size_t)r * K1P + c] = (h16)v;
  }
}

// stacked [WL; WR] -> fp16, K padded
__global__ __launch_bounds__(256) void conv_w2_kernel(const float* __restrict__ wl, const float* __restrict__ wr,
                                                      h16* __restrict__ o, int rows, int cols, int colsp) {
  int r = blockIdx.x;  // 0 .. 2*rows-1
  const float* s = (r < rows) ? (wl + (size_t)r * cols) : (wr + (size_t)(r - rows) * cols);
  for (int c = threadIdx.x; c < colsp; c += 256) {
    float v = (c < cols) ? s[c] : 0.f;
    o[(size_t)r * colsp + c] = (h16)v;
  }
}

// ---------- CSR build ----------
__global__ __launch_bounds__(256) void build_edges_kernel(const int* __restrict__ ei,
                                                          int* __restrict__ src, int* __restrict__ dst) {
  int e = blockIdx.x * 256 + threadIdx.x;
  if (e >= NE) return;
  if (e < NE0) { src[e] = ei[e]; dst[e] = ei[NE0 + e]; }
  else         { src[e] = e - NE0; dst[e] = e - NE0; }
}

__global__ __launch_bounds__(256) void deg_kernel(const int* __restrict__ dst, int* __restrict__ deg) {
  int e = blockIdx.x * 256 + threadIdx.x;
  if (e < NE) atomicAdd(&deg[dst[e]], 1);
}

__global__ __launch_bounds__(1024) void scan_kernel(const int* __restrict__ deg, int* __restrict__ rowptr) {
  __shared__ int b0[1024], b1[1024];
  __shared__ int carry;
  int t = threadIdx.x;
  if (t == 0) carry = 0;
  __syncthreads();
  for (int base = 0; base < NN; base += 1024) {
    int x = (base + t < NN) ? deg[base + t] : 0;
    b0[t] = x;
    __syncthreads();
    int* cur = b0; int* nxt = b1;
    for (int off = 1; off < 1024; off <<= 1) {
      int v = cur[t];
      if (t >= off) v += cur[t - off];
      nxt[t] = v;
      __syncthreads();
      int* tmp = cur; cur = nxt; nxt = tmp;
    }
    if (base + t < NN) rowptr[base + t] = carry + cur[t] - x;  // exclusive
    __syncthreads();
    if (t == 0) carry += cur[1023];
    __syncthreads();
  }
  if (t == 0) rowptr[NN] = carry;
}

__global__ __launch_bounds__(256) void scatter_kernel(const int* __restrict__ src, const int* __restrict__ dst,
                                                      const int* __restrict__ rowptr, int* __restrict__ cursor,
                                                      int* __restrict__ esrc) {
  int e = blockIdx.x * 256 + threadIdx.x;
  if (e >= NE) return;
  int d = dst[e];
  int pos = rowptr[d] + atomicAdd(&cursor[d], 1);
  esrc[pos] = src[e];
}

// ---------- fp16 MFMA GEMM, 256x256 tile, BK=64, 8 waves, counted-vmcnt pipeline ----------
// C[M,Nw] = A[M,K] * B[Nw,K]^T.  K % 64 == 0, K/64 >= 2.  M,Nw % 256 == 0.
// LDS: 2 buffers x (A 256x64 + B 256x64) fp16 = 128 KiB. Linear LDS dest for
// global_load_lds; source pre-swizzled (u_g = u_phys ^ (row&7)); ds_read applies
// the same XOR -> 2-way (free) bank aliasing instead of 16-way.
__global__ __launch_bounds__(512, 2) void gemm256_kernel(const h16* __restrict__ A, const h16* __restrict__ B,
                                                         h16* __restrict__ Co, int K, int Nw, int ntN) {
  __shared__ __align__(16) h16 lds[4 * 16384];  // [buf][mat] regions of 256x64
  int nwg = gridDim.x;
  int q = nwg >> 3, r = nwg & 7;
  int xc = blockIdx.x & 7, idx = blockIdx.x >> 3;
  int logical = (xc < r ? xc * (q + 1) : r * (q + 1) + (xc - r) * q) + idx;
  int tm = (logical / ntN) * 256, tn = (logical % ntN) * 256;

  int tid = threadIdx.x;
  int wv = tid >> 6, lane = tid & 63;
  int wm = (wv >> 2) * 128, wn = (wv & 3) * 64;
  int lrow = lane & 15, kq = lane >> 4, lr7 = lrow & 7;

  // staging constants: thread -> (row tid>>3 within 64-row round, phys unit tid&7)
  int rowoff = tid >> 3;
  int ug = ((tid & 7) ^ (rowoff & 7)) * 8;  // pre-swizzled global 16B-unit (in h16 elems)
  int ldsoff = (tid >> 6) * 512;            // (wv*8 rows)*64 elems; + j*64*64 per round

  const int NT = K >> 6;

  auto STAGE = [&](int buf, int kt) {
#pragma unroll
    for (int j = 0; j < 4; ++j) {
      GLDS16(A + (size_t)(tm + j * 64 + rowoff) * K + kt * 64 + ug,
             &lds[(buf * 2 + 0) * 16384 + j * 4096 + ldsoff]);
      GLDS16(B + (size_t)(tn + j * 64 + rowoff) * K + kt * 64 + ug,
             &lds[(buf * 2 + 1) * 16384 + j * 4096 + ldsoff]);
    }
  };

  STAGE(0, 0);
  STAGE(1, 1);

  f32x4 acc[8][4] = {};
  for (int t = 0; t < NT; ++t) {
    int b = t & 1;
    if (t + 1 < NT) { asm volatile("s_waitcnt vmcnt(8)" ::: "memory"); }
    else            { asm volatile("s_waitcnt vmcnt(0)" ::: "memory"); }
    __builtin_amdgcn_s_barrier();  // all waves' portions of buffer b have landed

    const h16* As_ = &lds[(b * 2 + 0) * 16384];
    const h16* Bs_ = &lds[(b * 2 + 1) * 16384];
    h16x8 af[8], bf[4];
    // k-slice 0 (cols 0..31): logical unit u = kq
#pragma unroll
    for (int i = 0; i < 8; ++i) af[i] = *(const h16x8*)&As_[(wm + i * 16 + lrow) * 64 + ((kq ^ lr7) * 8)];
#pragma unroll
    for (int j = 0; j < 4; ++j) bf[j] = *(const h16x8*)&Bs_[(wn + j * 16 + lrow) * 64 + ((kq ^ lr7) * 8)];
#pragma unroll
    for (int i = 0; i < 8; ++i)
#pragma unroll
      for (int j = 0; j < 4; ++j)
        acc[i][j] = __builtin_amdgcn_mfma_f32_16x16x32_f16(af[i], bf[j], acc[i][j], 0, 0, 0);
    // k-slice 1 (cols 32..63): logical unit u = 4 + kq
#pragma unroll
    for (int i = 0; i < 8; ++i) af[i] = *(const h16x8*)&As_[(wm + i * 16 + lrow) * 64 + (((4 + kq) ^ lr7) * 8)];
#pragma unroll
    for (int j = 0; j < 4; ++j) bf[j] = *(const h16x8*)&Bs_[(wn + j * 16 + lrow) * 64 + (((4 + kq) ^ lr7) * 8)];
    asm volatile("s_waitcnt lgkmcnt(0)" ::: "memory");
    __builtin_amdgcn_sched_barrier(0);
    __builtin_amdgcn_s_barrier();  // all waves done reading buffer b -> safe to restage
    if (t + 2 < NT) STAGE(b, t + 2);
    __builtin_amdgcn_s_setprio(1);
#pragma unroll
    for (int i = 0; i < 8; ++i)
#pragma unroll
      for (int j = 0; j < 4; ++j)
        acc[i][j] = __builtin_amdgcn_mfma_f32_16x16x32_f16(af[i], bf[j], acc[i][j], 0, 0, 0);
    __builtin_amdgcn_s_setprio(0);
  }

  int cr = kq * 4, cc = lrow;
#pragma unroll
  for (int i = 0; i < 8; ++i)
#pragma unroll
    for (int j = 0; j < 4; ++j) {
      size_t base = (size_t)(tm + wm + i * 16 + cr) * Nw + (tn + wn + j * 16 + cc);
#pragma unroll
      for (int qq = 0; qq < 4; qq++) Co[base + (size_t)qq * Nw] = (h16)acc[i][j][qq];
    }
}

// ---------- fused score + online-softmax + aggregate (batched gathers) ----------
// X row layout: [ xl (H*CD) | xr (H*CD) ], stride S = 2*H*CD.
template <int H, int MODE>
__global__ __launch_bounds__(64 * H) void sagg_kernel(
    const h16* __restrict__ X, const int* __restrict__ rowptr, const int* __restrict__ esrc,
    const float* __restrict__ att, const float* __restrict__ bias,
    h16* __restrict__ outA, const int* __restrict__ batch,
    float* __restrict__ pooled, int* __restrict__ cnt) {
  constexpr int HC = H * CD, S = 2 * HC;
  int n = blockIdx.x;
  int tid = threadIdx.x, w = tid >> 6, lane = tid & 63;
  int cb = w * CD + lane * 4;

  float4 aw4 = *(const float4*)(att + cb);
  const float* aw = (const float*)&aw4;
  h16x4 xr4 = *(const h16x4*)(X + (size_t)n * S + HC + cb);
  float xr0 = (float)xr4[0], xr1 = (float)xr4[1], xr2 = (float)xr4[2], xr3 = (float)xr4[3];

  int beg = rowptr[n], end = rowptr[n + 1];
  float m = -1e30f, s = 0.f;
  float a0 = 0.f, a1 = 0.f, a2 = 0.f, a3 = 0.f;
  int i = beg;
  while (i < end) {
    int cn = end - i; if (cn > 8) cn = 8;
    int js[8];
    h16x4 xs[8];
#pragma unroll
    for (int k = 0; k < 8; ++k) js[k] = esrc[i + (k < cn ? k : cn - 1)];  // independent loads
#pragma unroll
    for (int k = 0; k < 8; ++k) xs[k] = *(const h16x4*)(X + (size_t)js[k] * S + cb);  // batched gathers
#pragma unroll
    for (int k = 0; k < 8; ++k) {
      if (k < cn) {
        float x0 = (float)xs[k][0], x1 = (float)xs[k][1], x2 = (float)xs[k][2], x3 = (float)xs[k][3];
        float v0 = x0 + xr0, v1 = x1 + xr1, v2 = x2 + xr2, v3 = x3 + xr3;
        v0 = v0 > 0.f ? v0 : SLOPE * v0;
        v1 = v1 > 0.f ? v1 : SLOPE * v1;
        v2 = v2 > 0.f ? v2 : SLOPE * v2;
        v3 = v3 > 0.f ? v3 : SLOPE * v3;
        float p = v0 * aw[0] + v1 * aw[1] + v2 * aw[2] + v3 * aw[3];
        p += __shfl_xor(p, 32); p += __shfl_xor(p, 16); p += __shfl_xor(p, 8);
        p += __shfl_xor(p, 4);  p += __shfl_xor(p, 2);  p += __shfl_xor(p, 1);
        float nm = fmaxf(m, p);
        float f = __expf(m - nm), we = __expf(p - nm);
        s = s * f + we;
        a0 = a0 * f + we * x0; a1 = a1 * f + we * x1;
        a2 = a2 * f + we * x2; a3 = a3 * f + we * x3;
        m = nm;
      }
    }
    i += cn;
  }
  float inv = 1.f / (s + 1e-16f);

  if (MODE == 0) {
    float o0 = a0 * inv + bias[cb + 0];
    float o1 = a1 * inv + bias[cb + 1];
    float o2 = a2 * inv + bias[cb + 2];
    float o3 = a3 * inv + bias[cb + 3];
    o0 = o0 > 0.f ? o0 : expm1f(o0);
    o1 = o1 > 0.f ? o1 : expm1f(o1);
    o2 = o2 > 0.f ? o2 : expm1f(o2);
    o3 = o3 > 0.f ? o3 : expm1f(o3);
    h16x4 ov = {(h16)o0, (h16)o1, (h16)o2, (h16)o3};
    *(h16x4*)(outA + (size_t)n * HC + cb) = ov;
  } else {
    __shared__ float sh[HC];
    __shared__ float red[H];
    float4 nv = {a0 * inv, a1 * inv, a2 * inv, a3 * inv};
    *(float4*)&sh[cb] = nv;
    __syncthreads();
    float mv = 0.f;
    if (tid < CD) {
#pragma unroll
      for (int h = 0; h < H; h++) mv += sh[h * CD + tid];
      mv = mv * (1.f / H) + bias[tid];
    }
    float ss = (tid < CD) ? mv * mv : 0.f;
    ss += __shfl_xor(ss, 32); ss += __shfl_xor(ss, 16); ss += __shfl_xor(ss, 8);
    ss += __shfl_xor(ss, 4);  ss += __shfl_xor(ss, 2);  ss += __shfl_xor(ss, 1);
    if (lane == 0) red[w] = ss;
    __syncthreads();
    float tot = 0.f;
#pragma unroll
    for (int h = 0; h < H; h++) tot += red[h];
    float scale = 1.f / fmaxf(sqrtf(tot), 1e-12f);
    int g = batch[n];
    if (tid < CD) atomicAdd(&pooled[(size_t)g * CD + tid], mv * scale);
    if (tid == 0) atomicAdd(&cnt[g], 1);
  }
}

// ---------- pooled epilogue ----------
__global__ __launch_bounds__(256) void pool_div_kernel(float* __restrict__ pooled, const int* __restrict__ cnt) {
  int g = blockIdx.x, t = threadIdx.x;
  pooled[(size_t)g * CD + t] /= fmaxf((float)cnt[g], 1.f);
}

__global__ __launch_bounds__(256) void mlp1_kernel(const float* __restrict__ pooled, const float* __restrict__ w,
                                                   const float* __restrict__ b, float* __restrict__ hid) {
  __shared__ float xs[CD];
  int g = blockIdx.x, t = threadIdx.x;
  xs[t] = pooled[(size_t)g * CD + t];
  __syncthreads();
  float acc = b[t];
  for (int k = 0; k < CD; ++k) acc += xs[k] * w[(size_t)t * CD + k];
  hid[(size_t)g * CD + t] = fmaxf(acc, 0.f);
}

__global__ __launch_bounds__(256) void mlp2_kernel(const float* __restrict__ hid, const float* __restrict__ w,
                                                   const float* __restrict__ b, float* __restrict__ out) {
  __shared__ float xs[CD];
  int g = blockIdx.x, t = threadIdx.x;
  xs[t] = hid[(size_t)g * CD + t];
  __syncthreads();
  for (int o = t; o < 768; o += 256) {
    float acc = b[o];
    for (int k = 0; k < CD; ++k) acc += xs[k] * w[(size_t)o * CD + k];
    out[(size_t)g * 768 + o] = acc;
  }
}

extern "C" void kernel_launch(void* const* d_in, const int* in_sizes, int n_in,
                              void* d_out, int out_size, void* d_ws, size_t ws_size,
                              hipStream_t stream) {
  const float* x      = (const float*)d_in[0];
  const int*   ei     = (const int*)d_in[1];
  const int*   batch  = (const int*)d_in[2];
  const float* c1_wl  = (const float*)d_in[3];
  const float* c1_wr  = (const float*)d_in[4];
  const float* c1_att = (const float*)d_in[5];
  const float* c1_b   = (const float*)d_in[6];
  const float* c2_wl  = (const float*)d_in[7];
  const float* c2_wr  = (const float*)d_in[8];
  const float* c2_att = (const float*)d_in[9];
  const float* c2_b   = (const float*)d_in[10];
  const float* c3_wl  = (const float*)d_in[11];
  const float* c3_wr  = (const float*)d_in[12];
  const float* c3_att = (const float*)d_in[13];
  const float* c3_b   = (const float*)d_in[14];
  const float* fp1_w  = (const float*)d_in[15];
  const float* fp1_b  = (const float*)d_in[16];
  const float* fp2_w  = (const float*)d_in[17];
  const float* fp2_b  = (const float*)d_in[18];

  char* p = (char*)d_ws;
  size_t off = 0;
  auto alloc = [&](size_t b) { void* r = p + off; off += (b + 255) & ~(size_t)255; return r; };
  h16*  A    = (h16*)alloc((size_t)NPAD * 1024 * 2);   // conv in/out feature buffer
  h16*  Xa   = (h16*)alloc((size_t)NPAD * 3072 * 2);   // X1 (2048 used) and X3 (3072)
  h16*  Xb   = (h16*)alloc((size_t)NPAD * 2048 * 2);   // X2; A1 aliases its head
  h16*  A1   = Xb;                                     // [NPAD][384] fp16 input (dead before X2 written)
  h16*  W1   = (h16*)alloc((size_t)2048 * K1P * 2);
  h16*  W2   = (h16*)alloc((size_t)2048 * 1024 * 2);
  h16*  W3   = (h16*)alloc((size_t)3072 * 1024 * 2);
  int*  srcA   = (int*)alloc((size_t)NE * 4);
  int*  dstA   = (int*)alloc((size_t)NE * 4);
  int*  esrc   = (int*)alloc((size_t)NE * 4);
  int*  deg    = (int*)alloc((size_t)NN * 4);
  int*  cursor = (int*)alloc((size_t)NN * 4);
  int*  rowptr = (int*)alloc((size_t)(NN + 1) * 4);
  float* pooled = (float*)alloc((size_t)NG * CD * 4);
  int*  cnt    = (int*)alloc((size_t)NG * 4);
  float* hid   = (float*)alloc((size_t)NG * CD * 4);

  hipMemsetAsync(deg, 0, (size_t)NN * 4, stream);
  hipMemsetAsync(cursor, 0, (size_t)NN * 4, stream);
  hipMemsetAsync(pooled, 0, (size_t)NG * CD * 4, stream);
  hipMemsetAsync(cnt, 0, (size_t)NG * 4, stream);

  fill_x_kernel<<<NPAD, 256, 0, stream>>>(x, A1);
  conv_w2_kernel<<<2048, 256, 0, stream>>>(c1_wl, c1_wr, W1, 1024, FIN, K1P);
  conv_w2_kernel<<<2048, 256, 0, stream>>>(c2_wl, c2_wr, W2, 1024, 1024, 1024);
  conv_w2_kernel<<<3072, 256, 0, stream>>>(c3_wl, c3_wr, W3, 1536, 1024, 1024);

  int eb = (NE + 255) / 256;
  build_edges_kernel<<<eb, 256, 0, stream>>>(ei, srcA, dstA);
  deg_kernel<<<eb, 256, 0, stream>>>(dstA, deg);
  scan_kernel<<<1, 1024, 0, stream>>>(deg, rowptr);
  scatter_kernel<<<eb, 256, 0, stream>>>(srcA, dstA, rowptr, cursor, esrc);

  // conv1: [NPAD,384] x [2048,384]^T -> Xa [NPAD,2048] = [XL|XR]
  gemm256_kernel<<<79 * 8, 512, 0, stream>>>(A1, W1, Xa, K1P, 2048, 8);
  sagg_kernel<4, 0><<<NN, 256, 0, stream>>>(Xa, rowptr, esrc, c1_att, c1_b, A, nullptr, nullptr, nullptr);

  // conv2: [NPAD,1024] x [2048,1024]^T -> Xb
  gemm256_kernel<<<79 * 8, 512, 0, stream>>>(A, W2, Xb, 1024, 2048, 8);
  sagg_kernel<4, 0><<<NN, 256, 0, stream>>>(Xb, rowptr, esrc, c2_att, c2_b, A, nullptr, nullptr, nullptr);

  // conv3: [NPAD,1024] x [3072,1024]^T -> Xa [NPAD,3072]
  gemm256_kernel<<<79 * 12, 512, 0, stream>>>(A, W3, Xa, 1024, 3072, 12);
  sagg_kernel<6, 1><<<NN, 384, 0, stream>>>(Xa, rowptr, esrc, c3_att, c3_b, nullptr, batch, pooled, cnt);

  pool_div_kernel<<<NG, 256, 0, stream>>>(pooled, cnt);
  mlp1_kernel<<<NG, 256, 0, stream>>>(pooled, fp1_w, fp1_b, hid);
  mlp2_kernel<<<NG, 256, 0, stream>>>(hid, fp2_w, fp2_b, (float*)d_out);
}

// Round 4
// 701.669 us; speedup vs baseline: 1.9784x; 1.0346x over previous
//
#include <hip/hip_runtime.h>

typedef _Float16 h16;
typedef _Float16 h16x2 __attribute__((ext_vector_type(2)));
typedef _Float16 h16x4 __attribute__((ext_vector_type(4)));
typedef _Float16 h16x8 __attribute__((ext_vector_type(8)));
typedef float f32x4 __attribute__((ext_vector_type(4)));

static constexpr int NN   = 20000;   // nodes
static constexpr int NPAD = 20224;   // padded to 256-row tiles (79*256)
static constexpr int NE0  = 120000;  // raw edges
static constexpr int NE   = 140000;  // + self loops
static constexpr int NG   = 512;     // graphs
static constexpr int FIN  = 300;
static constexpr int K1P  = 384;     // FIN padded to K%64==0 (3 BK-iters)
static constexpr int CD   = 256;     // channels per head
static constexpr float SLOPE = 0.2f;

#define GLDS16(gsrc, ldst)                                                              \
  __builtin_amdgcn_global_load_lds(                                                    \
      (const __attribute__((address_space(1))) unsigned int*)(gsrc),                    \
      (__attribute__((address_space(3))) unsigned int*)(ldst), 16, 0, 0)

// ---------- input conversion ----------
__global__ __launch_bounds__(256) void fill_x_kernel(const float* __restrict__ x, h16* __restrict__ a1) {
  int r = blockIdx.x;
  for (int c = threadIdx.x; c < K1P; c += 256) {
    float v = (r < NN && c < FIN) ? x[(size_t)r * FIN + c] : 0.f;
    a1[(size_t)r * K1P + c] = (h16)v;
  }
}

// stacked [WL; WR] -> fp16, K padded
__global__ __launch_bounds__(256) void conv_w2_kernel(const float* __restrict__ wl, const float* __restrict__ wr,
                                                      h16* __restrict__ o, int rows, int cols, int colsp) {
  int r = blockIdx.x;  // 0 .. 2*rows-1
  const float* s = (r < rows) ? (wl + (size_t)r * cols) : (wr + (size_t)(r - rows) * cols);
  for (int c = threadIdx.x; c < colsp; c += 256) {
    float v = (c < cols) ? s[c] : 0.f;
    o[(size_t)r * colsp + c] = (h16)v;
  }
}

__global__ __launch_bounds__(256) void attcvt_kernel(const float* __restrict__ a, h16* __restrict__ o, int n) {
  int i = blockIdx.x * 256 + threadIdx.x;
  if (i < n) o[i] = (h16)a[i];
}

// ---------- CSR build ----------
__global__ __launch_bounds__(256) void build_edges_kernel(const int* __restrict__ ei,
                                                          int* __restrict__ src, int* __restrict__ dst) {
  int e = blockIdx.x * 256 + threadIdx.x;
  if (e >= NE) return;
  if (e < NE0) { src[e] = ei[e]; dst[e] = ei[NE0 + e]; }
  else         { src[e] = e - NE0; dst[e] = e - NE0; }
}

__global__ __launch_bounds__(256) void deg_kernel(const int* __restrict__ dst, int* __restrict__ deg) {
  int e = blockIdx.x * 256 + threadIdx.x;
  if (e < NE) atomicAdd(&deg[dst[e]], 1);
}

__global__ __launch_bounds__(1024) void scan_kernel(const int* __restrict__ deg, int* __restrict__ rowptr) {
  __shared__ int b0[1024], b1[1024];
  __shared__ int carry;
  int t = threadIdx.x;
  if (t == 0) carry = 0;
  __syncthreads();
  for (int base = 0; base < NN; base += 1024) {
    int x = (base + t < NN) ? deg[base + t] : 0;
    b0[t] = x;
    __syncthreads();
    int* cur = b0; int* nxt = b1;
    for (int off = 1; off < 1024; off <<= 1) {
      int v = cur[t];
      if (t >= off) v += cur[t - off];
      nxt[t] = v;
      __syncthreads();
      int* tmp = cur; cur = nxt; nxt = tmp;
    }
    if (base + t < NN) rowptr[base + t] = carry + cur[t] - x;  // exclusive
    __syncthreads();
    if (t == 0) carry += cur[1023];
    __syncthreads();
  }
  if (t == 0) rowptr[NN] = carry;
}

__global__ __launch_bounds__(256) void scatter_kernel(const int* __restrict__ src, const int* __restrict__ dst,
                                                      const int* __restrict__ rowptr, int* __restrict__ cursor,
                                                      int* __restrict__ esrc) {
  int e = blockIdx.x * 256 + threadIdx.x;
  if (e >= NE) return;
  int d = dst[e];
  int pos = rowptr[d] + atomicAdd(&cursor[d], 1);
  esrc[pos] = src[e];
}

// ---------- fp16 MFMA GEMM, 256x256 tile, BK=64, 8 waves, counted-vmcnt pipeline ----------
__global__ __launch_bounds__(512, 2) void gemm256_kernel(const h16* __restrict__ A, const h16* __restrict__ B,
                                                         h16* __restrict__ Co, int K, int Nw, int ntN) {
  __shared__ __align__(16) h16 lds[4 * 16384];  // [buf][mat] regions of 256x64
  int nwg = gridDim.x;
  int q = nwg >> 3, r = nwg & 7;
  int xc = blockIdx.x & 7, idx = blockIdx.x >> 3;
  int logical = (xc < r ? xc * (q + 1) : r * (q + 1) + (xc - r) * q) + idx;
  int tm = (logical / ntN) * 256, tn = (logical % ntN) * 256;

  int tid = threadIdx.x;
  int wv = tid >> 6, lane = tid & 63;
  int wm = (wv >> 2) * 128, wn = (wv & 3) * 64;
  int lrow = lane & 15, kq = lane >> 4, lr7 = lrow & 7;

  int rowoff = tid >> 3;
  int ug = ((tid & 7) ^ (rowoff & 7)) * 8;  // pre-swizzled global 16B-unit (in h16 elems)
  int ldsoff = (tid >> 6) * 512;

  const int NT = K >> 6;

  auto STAGE = [&](int buf, int kt) {
#pragma unroll
    for (int j = 0; j < 4; ++j) {
      GLDS16(A + (size_t)(tm + j * 64 + rowoff) * K + kt * 64 + ug,
             &lds[(buf * 2 + 0) * 16384 + j * 4096 + ldsoff]);
      GLDS16(B + (size_t)(tn + j * 64 + rowoff) * K + kt * 64 + ug,
             &lds[(buf * 2 + 1) * 16384 + j * 4096 + ldsoff]);
    }
  };

  STAGE(0, 0);
  STAGE(1, 1);

  f32x4 acc[8][4] = {};
  for (int t = 0; t < NT; ++t) {
    int b = t & 1;
    if (t + 1 < NT) { asm volatile("s_waitcnt vmcnt(8)" ::: "memory"); }
    else            { asm volatile("s_waitcnt vmcnt(0)" ::: "memory"); }
    __builtin_amdgcn_s_barrier();  // all waves' portions of buffer b have landed

    const h16* As_ = &lds[(b * 2 + 0) * 16384];
    const h16* Bs_ = &lds[(b * 2 + 1) * 16384];
    h16x8 af[8], bf[4];
#pragma unroll
    for (int i = 0; i < 8; ++i) af[i] = *(const h16x8*)&As_[(wm + i * 16 + lrow) * 64 + ((kq ^ lr7) * 8)];
#pragma unroll
    for (int j = 0; j < 4; ++j) bf[j] = *(const h16x8*)&Bs_[(wn + j * 16 + lrow) * 64 + ((kq ^ lr7) * 8)];
#pragma unroll
    for (int i = 0; i < 8; ++i)
#pragma unroll
      for (int j = 0; j < 4; ++j)
        acc[i][j] = __builtin_amdgcn_mfma_f32_16x16x32_f16(af[i], bf[j], acc[i][j], 0, 0, 0);
#pragma unroll
    for (int i = 0; i < 8; ++i) af[i] = *(const h16x8*)&As_[(wm + i * 16 + lrow) * 64 + (((4 + kq) ^ lr7) * 8)];
#pragma unroll
    for (int j = 0; j < 4; ++j) bf[j] = *(const h16x8*)&Bs_[(wn + j * 16 + lrow) * 64 + (((4 + kq) ^ lr7) * 8)];
    asm volatile("s_waitcnt lgkmcnt(0)" ::: "memory");
    __builtin_amdgcn_sched_barrier(0);
    __builtin_amdgcn_s_barrier();  // all waves done reading buffer b -> safe to restage
    if (t + 2 < NT) STAGE(b, t + 2);
    __builtin_amdgcn_s_setprio(1);
#pragma unroll
    for (int i = 0; i < 8; ++i)
#pragma unroll
      for (int j = 0; j < 4; ++j)
        acc[i][j] = __builtin_amdgcn_mfma_f32_16x16x32_f16(af[i], bf[j], acc[i][j], 0, 0, 0);
    __builtin_amdgcn_s_setprio(0);
  }

  int cr = kq * 4, cc = lrow;
#pragma unroll
  for (int i = 0; i < 8; ++i)
#pragma unroll
    for (int j = 0; j < 4; ++j) {
      size_t base = (size_t)(tm + wm + i * 16 + cr) * Nw + (tn + wn + j * 16 + cc);
#pragma unroll
      for (int qq = 0; qq < 4; qq++) Co[base + (size_t)qq * Nw] = (h16)acc[i][j][qq];
    }
}

// ---------- fused score + online-softmax + aggregate (pk-fp16 + fdot2 + defer-max) ----------
// X row layout: [ xl (H*CD) | xr (H*CD) ], stride S = 2*H*CD.
template <int H, int MODE>
__global__ __launch_bounds__(64 * H) void sagg_kernel(
    const h16* __restrict__ X, const int* __restrict__ rowptr, const int* __restrict__ esrc,
    const h16* __restrict__ attH, const float* __restrict__ bias,
    h16* __restrict__ outA, const int* __restrict__ batch,
    float* __restrict__ pooled, int* __restrict__ cnt) {
  constexpr int HC = H * CD, S = 2 * HC;
  int n = blockIdx.x;
  int tid = threadIdx.x, w = tid >> 6, lane = tid & 63;
  int cb = w * CD + lane * 4;

  h16x4 aw4 = *(const h16x4*)(attH + cb);
  h16x2 alo = __builtin_shufflevector(aw4, aw4, 0, 1);
  h16x2 ahi = __builtin_shufflevector(aw4, aw4, 2, 3);
  h16x4 xr4 = *(const h16x4*)(X + (size_t)n * S + HC + cb);

  int beg = rowptr[n], end = rowptr[n + 1];
  float m = -1e30f, s = 0.f;
  f32x4 a = {};
  int i = beg;
  while (i < end) {
    int cn = end - i; if (cn > 8) cn = 8;
    int js[8];
    h16x4 xs[8];
    float ps[8];
#pragma unroll
    for (int k = 0; k < 8; ++k) js[k] = esrc[i + (k < cn ? k : cn - 1)];  // independent loads
#pragma unroll
    for (int k = 0; k < 8; ++k) xs[k] = *(const h16x4*)(X + (size_t)js[k] * S + cb);  // batched gathers
#pragma unroll
    for (int k = 0; k < 8; ++k) {
      h16x4 v = xs[k] + xr4;                       // v_pk_add_f16
      h16x4 t = v * (h16)SLOPE;                    // v_pk_mul_f16
      v = __builtin_elementwise_max(v, t);         // leaky_relu = max(x, 0.2x): v_pk_max_f16
      float p = __builtin_amdgcn_fdot2(__builtin_shufflevector(v, v, 0, 1), alo,
                __builtin_amdgcn_fdot2(__builtin_shufflevector(v, v, 2, 3), ahi, 0.f, false), false);
      p += __shfl_xor(p, 32); p += __shfl_xor(p, 16); p += __shfl_xor(p, 8);
      p += __shfl_xor(p, 4);  p += __shfl_xor(p, 2);  p += __shfl_xor(p, 1);
      ps[k] = p;
    }
#pragma unroll
    for (int k = 0; k < 8; ++k) {
      if (k < cn) {
        float p = ps[k];
        if (p <= m) {            // wave-uniform branch: no rescale (common case)
          float we = __expf(p - m);
          s += we;
          a[0] += we * (float)xs[k][0]; a[1] += we * (float)xs[k][1];
          a[2] += we * (float)xs[k][2]; a[3] += we * (float)xs[k][3];
        } else {                 // new max: rescale, we = 1
          float f = __expf(m - p);
          s = s * f + 1.f;
          a[0] = a[0] * f + (float)xs[k][0]; a[1] = a[1] * f + (float)xs[k][1];
          a[2] = a[2] * f + (float)xs[k][2]; a[3] = a[3] * f + (float)xs[k][3];
          m = p;
        }
      }
    }
    i += cn;
  }
  float inv = 1.f / (s + 1e-16f);

  if (MODE == 0) {
    float o0 = a[0] * inv + bias[cb + 0];
    float o1 = a[1] * inv + bias[cb + 1];
    float o2 = a[2] * inv + bias[cb + 2];
    float o3 = a[3] * inv + bias[cb + 3];
    o0 = o0 > 0.f ? o0 : expm1f(o0);
    o1 = o1 > 0.f ? o1 : expm1f(o1);
    o2 = o2 > 0.f ? o2 : expm1f(o2);
    o3 = o3 > 0.f ? o3 : expm1f(o3);
    h16x4 ov = {(h16)o0, (h16)o1, (h16)o2, (h16)o3};
    *(h16x4*)(outA + (size_t)n * HC + cb) = ov;
  } else {
    __shared__ float sh[HC];
    __shared__ float red[H];
    float4 nv = {a[0] * inv, a[1] * inv, a[2] * inv, a[3] * inv};
    *(float4*)&sh[cb] = nv;
    __syncthreads();
    float mv = 0.f;
    if (tid < CD) {
#pragma unroll
      for (int h = 0; h < H; h++) mv += sh[h * CD + tid];
      mv = mv * (1.f / H) + bias[tid];
    }
    float ss = (tid < CD) ? mv * mv : 0.f;
    ss += __shfl_xor(ss, 32); ss += __shfl_xor(ss, 16); ss += __shfl_xor(ss, 8);
    ss += __shfl_xor(ss, 4);  ss += __shfl_xor(ss, 2);  ss += __shfl_xor(ss, 1);
    if (lane == 0) red[w] = ss;
    __syncthreads();
    float tot = 0.f;
#pragma unroll
    for (int h = 0; h < H; h++) tot += red[h];
    float scale = 1.f / fmaxf(sqrtf(tot), 1e-12f);
    int g = batch[n];
    if (tid < CD) atomicAdd(&pooled[(size_t)g * CD + tid], mv * scale);
    if (tid == 0) atomicAdd(&cnt[g], 1);
  }
}

// ---------- pooled epilogue ----------
__global__ __launch_bounds__(256) void pool_div_kernel(float* __restrict__ pooled, const int* __restrict__ cnt) {
  int g = blockIdx.x, t = threadIdx.x;
  pooled[(size_t)g * CD + t] /= fmaxf((float)cnt[g], 1.f);
}

__global__ __launch_bounds__(256) void mlp1_kernel(const float* __restrict__ pooled, const float* __restrict__ w,
                                                   const float* __restrict__ b, float* __restrict__ hid) {
  __shared__ float xs[CD];
  int g = blockIdx.x, t = threadIdx.x;
  xs[t] = pooled[(size_t)g * CD + t];
  __syncthreads();
  float acc = b[t];
  for (int k = 0; k < CD; ++k) acc += xs[k] * w[(size_t)t * CD + k];
  hid[(size_t)g * CD + t] = fmaxf(acc, 0.f);
}

__global__ __launch_bounds__(256) void mlp2_kernel(const float* __restrict__ hid, const float* __restrict__ w,
                                                   const float* __restrict__ b, float* __restrict__ out) {
  __shared__ float xs[CD];
  int g = blockIdx.x, t = threadIdx.x;
  xs[t] = hid[(size_t)g * CD + t];
  __syncthreads();
  for (int o = t; o < 768; o += 256) {
    float acc = b[o];
    for (int k = 0; k < CD; ++k) acc += xs[k] * w[(size_t)o * CD + k];
    out[(size_t)g * 768 + o] = acc;
  }
}

extern "C" void kernel_launch(void* const* d_in, const int* in_sizes, int n_in,
                              void* d_out, int out_size, void* d_ws, size_t ws_size,
                              hipStream_t stream) {
  const float* x      = (const float*)d_in[0];
  const int*   ei     = (const int*)d_in[1];
  const int*   batch  = (const int*)d_in[2];
  const float* c1_wl  = (const float*)d_in[3];
  const float* c1_wr  = (const float*)d_in[4];
  const float* c1_att = (const float*)d_in[5];
  const float* c1_b   = (const float*)d_in[6];
  const float* c2_wl  = (const float*)d_in[7];
  const float* c2_wr  = (const float*)d_in[8];
  const float* c2_att = (const float*)d_in[9];
  const float* c2_b   = (const float*)d_in[10];
  const float* c3_wl  = (const float*)d_in[11];
  const float* c3_wr  = (const float*)d_in[12];
  const float* c3_att = (const float*)d_in[13];
  const float* c3_b   = (const float*)d_in[14];
  const float* fp1_w  = (const float*)d_in[15];
  const float* fp1_b  = (const float*)d_in[16];
  const float* fp2_w  = (const float*)d_in[17];
  const float* fp2_b  = (const float*)d_in[18];

  char* p = (char*)d_ws;
  size_t off = 0;
  auto alloc = [&](size_t b) { void* r = p + off; off += (b + 255) & ~(size_t)255; return r; };
  h16*  A    = (h16*)alloc((size_t)NPAD * 1024 * 2);   // conv in/out feature buffer
  h16*  Xa   = (h16*)alloc((size_t)NPAD * 3072 * 2);   // X1 (2048 used) and X3 (3072)
  h16*  Xb   = (h16*)alloc((size_t)NPAD * 2048 * 2);   // X2; A1 aliases its head
  h16*  A1   = Xb;                                     // [NPAD][384] fp16 input (dead before X2 written)
  h16*  W1   = (h16*)alloc((size_t)2048 * K1P * 2);
  h16*  W2   = (h16*)alloc((size_t)2048 * 1024 * 2);
  h16*  W3   = (h16*)alloc((size_t)3072 * 1024 * 2);
  h16*  attH1 = (h16*)alloc((size_t)4 * CD * 2);
  h16*  attH2 = (h16*)alloc((size_t)4 * CD * 2);
  h16*  attH3 = (h16*)alloc((size_t)6 * CD * 2);
  int*  srcA   = (int*)alloc((size_t)NE * 4);
  int*  dstA   = (int*)alloc((size_t)NE * 4);
  int*  esrc   = (int*)alloc((size_t)NE * 4);
  int*  deg    = (int*)alloc((size_t)NN * 4);
  int*  cursor = (int*)alloc((size_t)NN * 4);
  int*  rowptr = (int*)alloc((size_t)(NN + 1) * 4);
  float* pooled = (float*)alloc((size_t)NG * CD * 4);
  int*  cnt    = (int*)alloc((size_t)NG * 4);
  float* hid   = (float*)alloc((size_t)NG * CD * 4);

  hipMemsetAsync(deg, 0, (size_t)NN * 4, stream);
  hipMemsetAsync(cursor, 0, (size_t)NN * 4, stream);
  hipMemsetAsync(pooled, 0, (size_t)NG * CD * 4, stream);
  hipMemsetAsync(cnt, 0, (size_t)NG * 4, stream);

  fill_x_kernel<<<NPAD, 256, 0, stream>>>(x, A1);
  conv_w2_kernel<<<2048, 256, 0, stream>>>(c1_wl, c1_wr, W1, 1024, FIN, K1P);
  conv_w2_kernel<<<2048, 256, 0, stream>>>(c2_wl, c2_wr, W2, 1024, 1024, 1024);
  conv_w2_kernel<<<3072, 256, 0, stream>>>(c3_wl, c3_wr, W3, 1536, 1024, 1024);
  attcvt_kernel<<<4, 256, 0, stream>>>(c1_att, attH1, 4 * CD);
  attcvt_kernel<<<4, 256, 0, stream>>>(c2_att, attH2, 4 * CD);
  attcvt_kernel<<<6, 256, 0, stream>>>(c3_att, attH3, 6 * CD);

  int eb = (NE + 255) / 256;
  build_edges_kernel<<<eb, 256, 0, stream>>>(ei, srcA, dstA);
  deg_kernel<<<eb, 256, 0, stream>>>(dstA, deg);
  scan_kernel<<<1, 1024, 0, stream>>>(deg, rowptr);
  scatter_kernel<<<eb, 256, 0, stream>>>(srcA, dstA, rowptr, cursor, esrc);

  // conv1: [NPAD,384] x [2048,384]^T -> Xa [NPAD,2048] = [XL|XR]
  gemm256_kernel<<<79 * 8, 512, 0, stream>>>(A1, W1, Xa, K1P, 2048, 8);
  sagg_kernel<4, 0><<<NN, 256, 0, stream>>>(Xa, rowptr, esrc, attH1, c1_b, A, nullptr, nullptr, nullptr);

  // conv2: [NPAD,1024] x [2048,1024]^T -> Xb
  gemm256_kernel<<<79 * 8, 512, 0, stream>>>(A, W2, Xb, 1024, 2048, 8);
  sagg_kernel<4, 0><<<NN, 256, 0, stream>>>(Xb, rowptr, esrc, attH2, c2_b, A, nullptr, nullptr, nullptr);

  // conv3: [NPAD,1024] x [3072,1024]^T -> Xa [NPAD,3072]
  gemm256_kernel<<<79 * 12, 512, 0, stream>>>(A, W3, Xa, 1024, 3072, 12);
  sagg_kernel<6, 1><<<NN, 384, 0, stream>>>(Xa, rowptr, esrc, attH3, c3_b, nullptr, batch, pooled, cnt);

  pool_div_kernel<<<NG, 256, 0, stream>>>(pooled, cnt);
  mlp1_kernel<<<NG, 256, 0, stream>>>(pooled, fp1_w, fp1_b, hid);
  mlp2_kernel<<<NG, 256, 0, stream>>>(hid, fp2_w, fp2_b, (float*)d_out);
}